// Round 12
// baseline (68.186 us; speedup 1.0000x reference)
//
#include <hip/hip_runtime.h>

// Problem constants (reference: B=1, T=2048, H=32, D=64, SCALE=1/64, DEG=2)
#define T_DIM 2048
#define H_DIM 32
#define D_DIM 64
#define SCALE_F 0.015625f
#define TILE_STRIDE 2048    // ushorts per (h, 32-row frag tile) = 4KB

typedef unsigned short ushort;
typedef __attribute__((ext_vector_type(8))) short short8;   // 8 bf16
typedef __attribute__((ext_vector_type(16))) float f32x16;  // 32x32 MFMA acc
typedef __attribute__((ext_vector_type(2))) float f32x2;
typedef __attribute__((ext_vector_type(4))) float f32x4;

#define MFMA32(A, B, C) __builtin_amdgcn_mfma_f32_32x32x16_bf16((A), (B), (C), 0, 0, 0)

// ---------------------------------------------------------------------------
// Kernel 1: per-head inclusive cumsum of g over T -> gc stored [H][T]  (B=1)
// ---------------------------------------------------------------------------
__global__ __launch_bounds__(256)
void cumsum_g_kernel(const float* __restrict__ g, float* __restrict__ gc) {
    const int h = blockIdx.x;
    const int tid = threadIdx.x;
    const int PER = T_DIM / 256;        // 8

    __shared__ float sums[256];

    float loc[8];
    float run = 0.f;
    const int t0 = tid * PER;
    for (int i = 0; i < PER; ++i) {
        run += g[(size_t)(t0 + i) * H_DIM + h];
        loc[i] = run;
    }
    sums[tid] = run;
    __syncthreads();

    for (int off = 1; off < 256; off <<= 1) {
        float vv = (tid >= off) ? sums[tid - off] : 0.f;
        __syncthreads();
        sums[tid] += vv;
        __syncthreads();
    }
    float excl = (tid == 0) ? 0.f : sums[tid - 1];

    for (int i = 0; i < PER; ++i)
        gc[(size_t)h * T_DIM + t0 + i] = excl + loc[i];
}

// ---------------------------------------------------------------------------
__device__ __forceinline__ ushort f2bf(float x) {
    unsigned u = __float_as_uint(x);
    unsigned r = (u + 0x7fffu + ((u >> 16) & 1u)) >> 16;
    return (ushort)r;
}

// ---------------------------------------------------------------------------
// Prep: frag-major bf16 buffers so ALL main-loop frag loads coalesce.
//   qfrag/kfrag: [h][t32][ks(4)][hi(2)][l31(32)][8]  content q̂/k̂[32*t32+l31][16ks+8hi+j]
//   vfrag:       [h][s32][dblk(2)][kh2(2)][hi(2)][l31(32)][8]
//                 content v̂[32*s32+16kh2+8hi+j][32dblk+l31]
// q̂ = q*SCALE*exp(gc/2), k̂ = k*exp(-gc/2), v̂ = bf16(v).  (Verified R5.)
// ---------------------------------------------------------------------------
__global__ __launch_bounds__(256)
void prep_kernel(const float* __restrict__ q, const float* __restrict__ k,
                 const float* __restrict__ v, const float* __restrict__ gc,
                 ushort* __restrict__ qfrag, ushort* __restrict__ kfrag,
                 ushort* __restrict__ vfrag) {
    __shared__ ushort qt_l[64 * 64];   // swizzled [row][slot] 16B chunks
    __shared__ ushort kt_l[64 * 64];

    const int h   = blockIdx.x;
    const int tt  = blockIdx.y;        // 64-row chunk
    const int tid = threadIdx.x;

    // ---- stage q̂,k̂ rows into swizzled LDS (coalesced f32 reads) ----
    {
        const int r    = tid >> 2;          // 0..63
        const int dseg = (tid & 3) * 16;    // 16 floats
        const int t    = tt * 64 + r;
        const float gct = gc[(size_t)h * T_DIM + t];
        const float eq = SCALE_F * __expf(0.5f * gct);
        const float ek = __expf(-0.5f * gct);
        const float* qp = q + ((size_t)t * H_DIM + h) * 64 + dseg;
        const float* kp = k + ((size_t)t * H_DIM + h) * 64 + dseg;
        union { ushort u[16]; uint4 uu[2]; } oq, ok;
#pragma unroll
        for (int i = 0; i < 16; ++i) {
            oq.u[i] = f2bf(qp[i] * eq);
            ok.u[i] = f2bf(kp[i] * ek);
        }
        const int c0 = (tid & 3) * 2;       // 16B chunk index base
#pragma unroll
        for (int cc = 0; cc < 2; ++cc) {
            const int slot = (c0 + cc) ^ (r & 7);
            *reinterpret_cast<uint4*>(&qt_l[r * 64 + slot * 8]) = oq.uu[cc];
            *reinterpret_cast<uint4*>(&kt_l[r * 64 + slot * 8]) = ok.uu[cc];
        }
    }
    __syncthreads();

    // ---- q/k frag writes: 512 16B-chunks each, coalesced stores ----
#pragma unroll
    for (int n = 0; n < 2; ++n) {
        const int ch   = tid + 256 * n;     // 0..511
        const int l31  = ch & 31;
        const int hi   = (ch >> 5) & 1;
        const int ks   = (ch >> 6) & 3;
        const int t32r = ch >> 8;           // 0/1
        const int row  = t32r * 32 + l31;
        const int slot = (2 * ks + hi) ^ (row & 7);
        uint4 qq = *reinterpret_cast<const uint4*>(&qt_l[row * 64 + slot * 8]);
        uint4 kk = *reinterpret_cast<const uint4*>(&kt_l[row * 64 + slot * 8]);
        const size_t base = ((size_t)h * 64 + tt * 2 + t32r) * TILE_STRIDE
                          + (size_t)(((ks * 2 + hi) * 32) + l31) * 8;
        *reinterpret_cast<uint4*>(qfrag + base) = qq;
        *reinterpret_cast<uint4*>(kfrag + base) = kk;
    }

    // ---- v frags: direct global gather (all loads/stores coalesced) ----
#pragma unroll
    for (int n = 0; n < 2; ++n) {
        const int c9   = (tid >> 5) + 8 * n;  // 0..15
        const int l31  = tid & 31;
        const int hi   = c9 & 1;
        const int kh2  = (c9 >> 1) & 1;
        const int dblk = (c9 >> 2) & 1;
        const int s32r = c9 >> 3;
        const int tb = tt * 64 + s32r * 32 + kh2 * 16 + hi * 8;
        union { ushort u[8]; uint4 uu; } ov;
#pragma unroll
        for (int j = 0; j < 8; ++j)
            ov.u[j] = f2bf(v[((size_t)(tb + j) * H_DIM + h) * 64 + dblk * 32 + l31]);
        const size_t base = ((size_t)h * 64 + tt * 2 + s32r) * TILE_STRIDE
                          + (size_t)((((dblk * 2 + kh2) * 2 + hi) * 32) + l31) * 8;
        *reinterpret_cast<uint4*>(vfrag + base) = ov.uu;
    }
}

// ---------------------------------------------------------------------------
// Main kernel helpers
// ---------------------------------------------------------------------------
__device__ __forceinline__ short8 ld8(const ushort* p) {
    return *reinterpret_cast<const short8*>(p);
}

__device__ __forceinline__ unsigned cvt_pk_bf16(float lo, float hi) {
    unsigned r;
    asm("v_cvt_pk_bf16_f32 %0, %1, %2" : "=v"(r) : "v"(lo), "v"(hi));
    return r;
}

// Pack 8 f32 W-values (4 f32x2 pairs, C-layout half) into the PV A-operand
// fragment via cvt_pk + permlane32_swap. (Layout verified R3-R11.)
__device__ __forceinline__ short8 pack_w2(const f32x2* w2) {
    unsigned p0 = cvt_pk_bf16(w2[0][0], w2[0][1]);
    unsigned p1 = cvt_pk_bf16(w2[1][0], w2[1][1]);
    unsigned p2 = cvt_pk_bf16(w2[2][0], w2[2][1]);
    unsigned p3 = cvt_pk_bf16(w2[3][0], w2[3][1]);
    asm("v_permlane32_swap_b32 %0, %1" : "+v"(p0), "+v"(p2));
    asm("v_permlane32_swap_b32 %0, %1" : "+v"(p1), "+v"(p3));
    union { unsigned u[4]; short8 s; } af;
    af.u[0] = p0; af.u[1] = p1; af.u[2] = p2; af.u[3] = p3;
    return af.s;
}

// One 32s x 32q unit, frags loaded directly from global (L1/L2-resident,
// single coalesced dwordx4 each). MODE 0: full, 1: diag (s_local <= l31).
template<int MODE>
__device__ __forceinline__ void unitD(
    const ushort* __restrict__ kb, const ushort* __restrict__ vb,
    int lofs, int hi, int l31,
    const short8 (&qr)[4], f32x16& o0, f32x16& o1, f32x2& den2)
{
    const short8 kf0 = ld8(kb + lofs);
    const short8 kf1 = ld8(kb + 512 + lofs);
    const short8 kf2 = ld8(kb + 1024 + lofs);
    const short8 kf3 = ld8(kb + 1536 + lofs);
    const short8 vf0 = ld8(vb + lofs);           // dblk0 kh2=0
    const short8 vf1 = ld8(vb + 512 + lofs);     // dblk0 kh2=1
    const short8 vf2 = ld8(vb + 1024 + lofs);    // dblk1 kh2=0
    const short8 vf3 = ld8(vb + 1536 + lofs);    // dblk1 kh2=1

    f32x16 c;
#pragma unroll
    for (int i = 0; i < 16; ++i) c[i] = 0.f;
    c = MFMA32(kf0, qr[0], c);
    c = MFMA32(kf1, qr[1], c);
    c = MFMA32(kf2, qr[2], c);
    c = MFMA32(kf3, qr[3], c);

    f32x2 w2[8];
#pragma unroll
    for (int i = 0; i < 8; ++i) {
        const int r0 = 2 * i;
        f32x2 x; x[0] = c[r0]; x[1] = c[r0 + 1];
        f32x2 ww = x * x;
        if (MODE == 1) {
            const int sl0 = (r0 & 3) + 8 * (r0 >> 2) + 4 * hi;
            ww[0] = (sl0 <= l31) ? ww[0] : 0.f;
            ww[1] = (sl0 + 1 <= l31) ? ww[1] : 0.f;
        }
        w2[i] = ww;
        den2 += ww;
    }
    const short8 a0 = pack_w2(&w2[0]);     // kh2 = 0
    o0 = MFMA32(a0, vf0, o0);
    o1 = MFMA32(a0, vf2, o1);
    const short8 a1 = pack_w2(&w2[4]);     // kh2 = 1
    o0 = MFMA32(a1, vf1, o0);
    o1 = MFMA32(a1, vf3, o1);
}

// ---------------------------------------------------------------------------
// Kernel 3: split-Q pair-fold main. Grid 512 = 16 pairs x 32 heads (2/CU).
// 4 independent waves own one 32-row q-subtile each:
//   w0: 62-2p   w1: 63-2p   w2: 2p   w3: 2p+1     (130 units/block, uniform)
// All waves sweep s-tiles from 0 in lockstep -> L1 broadcast (x4 for
// s<=2p+1, x2 beyond). No barriers, no LDS, no merge: each wave writes its
// own rows. s-loop unrolled x2 (two independent MFMA chains in flight).
// ---------------------------------------------------------------------------
__global__ __launch_bounds__(256, 2)
void retention_main_kernel(const ushort* __restrict__ qfrag,
                           const ushort* __restrict__ kfrag,
                           const ushort* __restrict__ vfrag,
                           float* __restrict__ out) {
    const int bid  = blockIdx.x;
    const int h    = bid & 31;           // h%8 == bid%8 -> head-home XCD
    const int p    = bid >> 5;           // pair 0..15
    const int tid  = threadIdx.x;
    const int w    = tid >> 6;
    const int lane = tid & 63;
    const int hi   = lane >> 5;
    const int l31  = lane & 31;
    const int lofs = hi * 256 + l31 * 8;

    // subtile ownership (uniform 130 units/block)
    const int m = (w == 0) ? (62 - 2 * p)
                : (w == 1) ? (63 - 2 * p)
                : (w == 2) ? (2 * p)
                :            (2 * p + 1);

    // Q frags (16 VGPR)
    short8 qr[4];
    {
        const ushort* qb = qfrag + ((size_t)h * 64 + m) * TILE_STRIDE;
#pragma unroll
        for (int ks = 0; ks < 4; ++ks) qr[ks] = ld8(qb + ks * 512 + lofs);
    }

    f32x16 o0, o1;
#pragma unroll
    for (int i = 0; i < 16; ++i) { o0[i] = 0.f; o1[i] = 0.f; }
    f32x2 d2; d2[0] = 0.f; d2[1] = 0.f;

    const ushort* khb = kfrag + (size_t)h * 64 * TILE_STRIDE;
    const ushort* vhb = vfrag + (size_t)h * 64 * TILE_STRIDE;

    // full units, unrolled x2 (independent chains); all waves start at st=0
    int st = 0;
    for (; st + 1 < m; st += 2) {
        unitD<0>(khb + (size_t)st * TILE_STRIDE, vhb + (size_t)st * TILE_STRIDE,
                 lofs, hi, l31, qr, o0, o1, d2);
        unitD<0>(khb + (size_t)(st + 1) * TILE_STRIDE, vhb + (size_t)(st + 1) * TILE_STRIDE,
                 lofs, hi, l31, qr, o0, o1, d2);
    }
    if (st < m)
        unitD<0>(khb + (size_t)st * TILE_STRIDE, vhb + (size_t)st * TILE_STRIDE,
                 lofs, hi, l31, qr, o0, o1, d2);
    // diagonal unit
    unitD<1>(khb + (size_t)m * TILE_STRIDE, vhb + (size_t)m * TILE_STRIDE,
             lofs, hi, l31, qr, o0, o1, d2);

    // ---- epilogue: wave owns its rows outright ----
    float den = d2[0] + d2[1];
    den += __shfl_xor(den, 32);          // den for q-row l31 (both hi halves)

#pragma unroll
    for (int rr = 0; rr < 16; ++rr) {
        const int row = (rr & 3) + 8 * (rr >> 2) + 4 * hi;
        const float dt = __shfl(den, row);
        const float inv = 1.f / fmaxf(dt, 1.f);
        const int t = m * 32 + row;
        float* op = out + ((size_t)t * H_DIM + h) * 64;
        op[l31]      = o0[rr] * inv;
        op[32 + l31] = o1[rr] * inv;
    }
}

// ---------------------------------------------------------------------------
extern "C" void kernel_launch(void* const* d_in, const int* in_sizes, int n_in,
                              void* d_out, int out_size, void* d_ws, size_t ws_size,
                              hipStream_t stream) {
    const float* q = (const float*)d_in[0];
    const float* k = (const float*)d_in[1];
    const float* v = (const float*)d_in[2];
    const float* g = (const float*)d_in[3];
    float* out = (float*)d_out;

    const size_t GC_BYTES = (size_t)H_DIM * T_DIM * sizeof(float);   // 256 KB
    const size_t BF_ELEMS = (size_t)H_DIM * T_DIM * D_DIM;           // 4.2M ushorts

    float* gc = (float*)d_ws;
    ushort* qfrag = (ushort*)((char*)d_ws + GC_BYTES);
    ushort* kfrag = qfrag + BF_ELEMS;
    ushort* vfrag = kfrag + BF_ELEMS;

    cumsum_g_kernel<<<H_DIM, 256, 0, stream>>>(g, gc);
    prep_kernel<<<dim3(H_DIM, T_DIM / 64), 256, 0, stream>>>(q, k, v, gc,
                                                             qfrag, kfrag, vfrag);
    retention_main_kernel<<<512, 256, 0, stream>>>(qfrag, kfrag, vfrag, out);
}